// Round 1
// baseline (250.184 us; speedup 1.0000x reference)
//
#include <hip/hip_runtime.h>

#define TPB  256
#define MPB  256            // matrices per block
#define F4PB 576            // float4 chunks per block = MPB*9/4

// Jacobi rotation (c,s) that annihilates apq in the (p,q) plane.
__device__ __forceinline__ void jrot(float app, float aqq, float apq,
                                     float& c, float& s) {
    float tau = (aqq - app) * 0.5f * __builtin_amdgcn_rcpf(apq);
    float t = __builtin_amdgcn_rcpf(fabsf(tau) +
              __builtin_amdgcn_sqrtf(fmaf(tau, tau, 1.0f)));
    t = copysignf(t, tau);
    t = (fabsf(apq) < 1e-30f) ? 0.0f : t;   // guards apq==0 (tau=inf/nan path)
    c = __builtin_amdgcn_rsqf(fmaf(t, t, 1.0f));
    s = t * c;
}

__global__ __launch_bounds__(TPB)
void so3_proj_kernel(const float* __restrict__ Rc,
                     const float* __restrict__ Tt,
                     const float* __restrict__ Nz,
                     const float* __restrict__ Ez,
                     float* __restrict__ Out,
                     int L)
{
    __shared__ float4 lds4[F4PB];
    float* lds = (float*)lds4;

    const int tid = threadIdx.x;
    const long long base = (long long)blockIdx.x * MPB;
    const int n = (int)(base / (long long)L);     // uniform per block (256 | 8192)
    const float alpha = Tt[n];                    // BETA = 1
    const float sa = __builtin_amdgcn_sqrtf(alpha);

    const float4* R4 = (const float4*)(Rc + base * 9);
    const float4* N4 = (const float4*)(Nz + base * 9);
    const float4* E4 = (const float4*)(Ez + base * 9);
    float4*       O4 = (float4*)(Out + base * 9);

    // ---- stage F = alpha*R + sqrt(alpha)*noise + 1e-6*eps into LDS (vectorized)
    #pragma unroll
    for (int it = 0; it < 3; ++it) {
        int j = tid + it * TPB;
        if (j < F4PB) {
            float4 r = R4[j], z = N4[j], e = E4[j];
            float4 f;
            f.x = fmaf(alpha, r.x, fmaf(sa, z.x, 1e-6f * e.x));
            f.y = fmaf(alpha, r.y, fmaf(sa, z.y, 1e-6f * e.y));
            f.z = fmaf(alpha, r.z, fmaf(sa, z.z, 1e-6f * e.z));
            f.w = fmaf(alpha, r.w, fmaf(sa, z.w, 1e-6f * e.w));
            lds4[j] = f;
        }
    }
    __syncthreads();

    float F[9];
    #pragma unroll
    for (int k = 0; k < 9; ++k) F[k] = lds[tid * 9 + k];  // stride 9: 2-way alias, free

    // ---- A = F^T F (symmetric, 6 uniques)
    float a00 = F[0]*F[0] + F[3]*F[3] + F[6]*F[6];
    float a01 = F[0]*F[1] + F[3]*F[4] + F[6]*F[7];
    float a02 = F[0]*F[2] + F[3]*F[5] + F[6]*F[8];
    float a11 = F[1]*F[1] + F[4]*F[4] + F[7]*F[7];
    float a12 = F[1]*F[2] + F[4]*F[5] + F[7]*F[8];
    float a22 = F[2]*F[2] + F[5]*F[5] + F[8]*F[8];

    // ---- V accumulates Jacobi rotations (starts as identity)
    float v00=1.f, v01=0.f, v02=0.f;
    float v10=0.f, v11=1.f, v12=0.f;
    float v20=0.f, v21=0.f, v22=1.f;

    #pragma unroll
    for (int sweep = 0; sweep < 5; ++sweep) {
        float c, s, t0, t1;
        // pivot (0,1)
        jrot(a00, a11, a01, c, s);
        t0 = c*c*a00 - 2.f*c*s*a01 + s*s*a11;
        t1 = s*s*a00 + 2.f*c*s*a01 + c*c*a11;
        a00 = t0; a11 = t1; a01 = 0.f;
        t0 = c*a02 - s*a12; t1 = s*a02 + c*a12; a02 = t0; a12 = t1;
        t0 = c*v00 - s*v01; v01 = s*v00 + c*v01; v00 = t0;
        t0 = c*v10 - s*v11; v11 = s*v10 + c*v11; v10 = t0;
        t0 = c*v20 - s*v21; v21 = s*v20 + c*v21; v20 = t0;
        // pivot (0,2)
        jrot(a00, a22, a02, c, s);
        t0 = c*c*a00 - 2.f*c*s*a02 + s*s*a22;
        t1 = s*s*a00 + 2.f*c*s*a02 + c*c*a22;
        a00 = t0; a22 = t1; a02 = 0.f;
        t0 = c*a01 - s*a12; t1 = s*a01 + c*a12; a01 = t0; a12 = t1;
        t0 = c*v00 - s*v02; v02 = s*v00 + c*v02; v00 = t0;
        t0 = c*v10 - s*v12; v12 = s*v10 + c*v12; v10 = t0;
        t0 = c*v20 - s*v22; v22 = s*v20 + c*v22; v20 = t0;
        // pivot (1,2)
        jrot(a11, a22, a12, c, s);
        t0 = c*c*a11 - 2.f*c*s*a12 + s*s*a22;
        t1 = s*s*a11 + 2.f*c*s*a12 + c*c*a22;
        a11 = t0; a22 = t1; a12 = 0.f;
        t0 = c*a01 - s*a02; t1 = s*a01 + c*a02; a01 = t0; a02 = t1;
        t0 = c*v01 - s*v02; v02 = s*v01 + c*v02; v01 = t0;
        t0 = c*v11 - s*v12; v12 = s*v11 + c*v12; v11 = t0;
        t0 = c*v21 - s*v22; v22 = s*v21 + c*v22; v21 = t0;
    }

    // ---- sort eigenpairs descending (columns of V move with eigenvalues)
    float l0 = a00, l1 = a11, l2 = a22;
    if (l0 < l1) { float t;
        t=l0;l0=l1;l1=t; t=v00;v00=v01;v01=t; t=v10;v10=v11;v11=t; t=v20;v20=v21;v21=t; }
    if (l0 < l2) { float t;
        t=l0;l0=l2;l2=t; t=v00;v00=v02;v02=t; t=v10;v10=v12;v12=t; t=v20;v20=v22;v22=t; }
    if (l1 < l2) { float t;
        t=l1;l1=l2;l2=t; t=v01;v01=v02;v02=t; t=v11;v11=v12;v12=t; t=v21;v21=v22;v22=t; }

    // v1 = col0 of V, v2 = col1; v3 = v1 x v2 (right-handed, unit)
    float v3x = v10*v21 - v20*v11;
    float v3y = v20*v01 - v00*v21;
    float v3z = v00*v11 - v10*v01;

    // u1 = normalize(F v1)
    float u1x = F[0]*v00 + F[1]*v10 + F[2]*v20;
    float u1y = F[3]*v00 + F[4]*v10 + F[5]*v20;
    float u1z = F[6]*v00 + F[7]*v10 + F[8]*v20;
    float inv1 = __builtin_amdgcn_rsqf(fmaxf(u1x*u1x + u1y*u1y + u1z*u1z, 1e-30f));
    u1x *= inv1; u1y *= inv1; u1z *= inv1;

    // u2 = normalize(F v2 - (u1 . F v2) u1)
    float wx = F[0]*v01 + F[1]*v11 + F[2]*v21;
    float wy = F[3]*v01 + F[4]*v11 + F[5]*v21;
    float wz = F[6]*v01 + F[7]*v11 + F[8]*v21;
    float dd = u1x*wx + u1y*wy + u1z*wz;
    wx -= dd*u1x; wy -= dd*u1y; wz -= dd*u1z;
    float inv2 = __builtin_amdgcn_rsqf(fmaxf(wx*wx + wy*wy + wz*wz, 1e-30f));
    float u2x = wx*inv2, u2y = wy*inv2, u2z = wz*inv2;

    // u3 = u1 x u2 (right-handed)
    float u3x = u1y*u2z - u1z*u2y;
    float u3y = u1z*u2x - u1x*u2z;
    float u3z = u1x*u2y - u1y*u2x;

    // R = u1 v1^T + u2 v2^T + u3 v3^T  ==  U diag(1,1,det(UV^T)) V^T
    float Rm[9];
    Rm[0] = u1x*v00 + u2x*v01 + u3x*v3x;
    Rm[1] = u1x*v10 + u2x*v11 + u3x*v3y;
    Rm[2] = u1x*v20 + u2x*v21 + u3x*v3z;
    Rm[3] = u1y*v00 + u2y*v01 + u3y*v3x;
    Rm[4] = u1y*v10 + u2y*v11 + u3y*v3y;
    Rm[5] = u1y*v20 + u2y*v21 + u3y*v3z;
    Rm[6] = u1z*v00 + u2z*v01 + u3z*v3x;
    Rm[7] = u1z*v10 + u2z*v11 + u3z*v3y;
    Rm[8] = u1z*v20 + u2z*v21 + u3z*v3z;

    // ---- stage result through LDS for vectorized store
    __syncthreads();
    #pragma unroll
    for (int k = 0; k < 9; ++k) lds[tid * 9 + k] = Rm[k];
    __syncthreads();

    #pragma unroll
    for (int it = 0; it < 3; ++it) {
        int j = tid + it * TPB;
        if (j < F4PB) O4[j] = lds4[j];
    }
}

extern "C" void kernel_launch(void* const* d_in, const int* in_sizes, int n_in,
                              void* d_out, int out_size, void* d_ws, size_t ws_size,
                              hipStream_t stream) {
    const float* Rc = (const float*)d_in[0];   // R_clean (N,L,3,3)
    const float* Tt = (const float*)d_in[1];   // t (N,)
    const float* Nz = (const float*)d_in[2];   // noise
    const float* Ez = (const float*)d_in[3];   // eps_noise
    float* Out = (float*)d_out;

    const long long mats = (long long)in_sizes[0] / 9;   // 2097152
    const int L = (int)(mats / in_sizes[1]);             // 8192
    const int blocks = (int)(mats / MPB);                // 8192

    so3_proj_kernel<<<blocks, TPB, 0, stream>>>(Rc, Tt, Nz, Ez, Out, L);
}

// Round 2
// 244.282 us; speedup vs baseline: 1.0242x; 1.0242x over previous
//
#include <hip/hip_runtime.h>

#define TPB  256
#define MPB  256            // matrices per block
#define F4PB 576            // float4 chunks per block = MPB*9/4

// Jacobi rotation annihilating apq in the (p,q) plane.
// t = sign(d) * 2*apq / (|d| + sqrt(d^2 + 4*apq^2)),  d = aqq - app.
// 3 transcendentals (sqrt, rcp, rsq); no divide-by-zero guard needed
// (apq==0 -> t==0; d==0 -> |t|==1, valid 45-degree rotation).
__device__ __forceinline__ void jrot(float app, float aqq, float apq,
                                     float& c, float& s, float& t) {
    float d  = aqq - app;
    float p2 = apq + apq;
    float rad = __builtin_amdgcn_sqrtf(fmaf(d, d, p2 * p2));
    float den = fmaxf(fabsf(d) + rad, 1e-38f);
    t = p2 * copysignf(__builtin_amdgcn_rcpf(den), d);
    c = __builtin_amdgcn_rsqf(fmaf(t, t, 1.0f));
    s = t * c;
}

__global__ __launch_bounds__(TPB)
void so3_proj_kernel(const float* __restrict__ Rc,
                     const float* __restrict__ Tt,
                     const float* __restrict__ Nz,
                     const float* __restrict__ Ez,
                     float* __restrict__ Out,
                     int L)
{
    __shared__ float4 lds4[F4PB];
    float* lds = (float*)lds4;

    const int tid = threadIdx.x;
    const long long base = (long long)blockIdx.x * MPB;
    const int n = (int)(base / (long long)L);     // uniform per block (256 | 8192)
    const float alpha = Tt[n];                    // BETA = 1
    const float sa = __builtin_amdgcn_sqrtf(alpha);

    const float4* R4 = (const float4*)(Rc + base * 9);
    const float4* N4 = (const float4*)(Nz + base * 9);
    const float4* E4 = (const float4*)(Ez + base * 9);
    float4*       O4 = (float4*)(Out + base * 9);

    // ---- stage F = alpha*R + sqrt(alpha)*noise + 1e-6*eps into LDS (vectorized)
    #pragma unroll
    for (int it = 0; it < 3; ++it) {
        int j = tid + it * TPB;
        if (j < F4PB) {
            float4 r = R4[j], z = N4[j], e = E4[j];
            float4 f;
            f.x = fmaf(alpha, r.x, fmaf(sa, z.x, 1e-6f * e.x));
            f.y = fmaf(alpha, r.y, fmaf(sa, z.y, 1e-6f * e.y));
            f.z = fmaf(alpha, r.z, fmaf(sa, z.z, 1e-6f * e.z));
            f.w = fmaf(alpha, r.w, fmaf(sa, z.w, 1e-6f * e.w));
            lds4[j] = f;
        }
    }
    __syncthreads();

    float F[9];
    #pragma unroll
    for (int k = 0; k < 9; ++k) F[k] = lds[tid * 9 + k];  // stride 9: 2-way alias, free

    // ---- A = F^T F (symmetric, 6 uniques)
    float a00 = F[0]*F[0] + F[3]*F[3] + F[6]*F[6];
    float a01 = F[0]*F[1] + F[3]*F[4] + F[6]*F[7];
    float a02 = F[0]*F[2] + F[3]*F[5] + F[6]*F[8];
    float a11 = F[1]*F[1] + F[4]*F[4] + F[7]*F[7];
    float a12 = F[1]*F[2] + F[4]*F[5] + F[7]*F[8];
    float a22 = F[2]*F[2] + F[5]*F[5] + F[8]*F[8];

    // ---- V accumulates Jacobi rotations (starts as identity)
    float v00=1.f, v01=0.f, v02=0.f;
    float v10=0.f, v11=1.f, v12=0.f;
    float v20=0.f, v21=0.f, v22=1.f;

    for (int sweep = 0; sweep < 5; ++sweep) {
        // wave-uniform early exit: after 3 sweeps, stop when all lanes converged.
        // 1e-13 is ~7x above the fp32 stagnation floor (~1.4e-14), so the exit
        // only fires when the extra sweeps would be no-ops.
        if (sweep >= 3) {
            float off = fmaf(a01, a01, fmaf(a02, a02, a12 * a12));
            float sc  = fmaf(a00, a00, fmaf(a11, a11, a22 * a22));
            if (__all(off <= 1e-13f * sc)) break;
        }
        float c, s, t, t0;
        // pivot (0,1)
        jrot(a00, a11, a01, c, s, t);
        a00 = fmaf(-t, a01, a00); a11 = fmaf(t, a01, a11); a01 = 0.f;
        t0 = c*a02 - s*a12; a12 = fmaf(s, a02, c*a12); a02 = t0;
        t0 = c*v00 - s*v01; v01 = fmaf(s, v00, c*v01); v00 = t0;
        t0 = c*v10 - s*v11; v11 = fmaf(s, v10, c*v11); v10 = t0;
        t0 = c*v20 - s*v21; v21 = fmaf(s, v20, c*v21); v20 = t0;
        // pivot (0,2)
        jrot(a00, a22, a02, c, s, t);
        a00 = fmaf(-t, a02, a00); a22 = fmaf(t, a02, a22); a02 = 0.f;
        t0 = c*a01 - s*a12; a12 = fmaf(s, a01, c*a12); a01 = t0;
        t0 = c*v00 - s*v02; v02 = fmaf(s, v00, c*v02); v00 = t0;
        t0 = c*v10 - s*v12; v12 = fmaf(s, v10, c*v12); v10 = t0;
        t0 = c*v20 - s*v22; v22 = fmaf(s, v20, c*v22); v20 = t0;
        // pivot (1,2)
        jrot(a11, a22, a12, c, s, t);
        a11 = fmaf(-t, a12, a11); a22 = fmaf(t, a12, a22); a12 = 0.f;
        t0 = c*a01 - s*a02; a02 = fmaf(s, a01, c*a02); a01 = t0;
        t0 = c*v01 - s*v02; v02 = fmaf(s, v01, c*v02); v01 = t0;
        t0 = c*v11 - s*v12; v12 = fmaf(s, v11, c*v12); v11 = t0;
        t0 = c*v21 - s*v22; v22 = fmaf(s, v21, c*v22); v21 = t0;
    }

    // ---- sort eigenpairs descending (columns of V move with eigenvalues)
    float l0 = a00, l1 = a11, l2 = a22;
    if (l0 < l1) { float t;
        t=l0;l0=l1;l1=t; t=v00;v00=v01;v01=t; t=v10;v10=v11;v11=t; t=v20;v20=v21;v21=t; }
    if (l0 < l2) { float t;
        t=l0;l0=l2;l2=t; t=v00;v00=v02;v02=t; t=v10;v10=v12;v12=t; t=v20;v20=v22;v22=t; }
    if (l1 < l2) { float t;
        t=l1;l1=l2;l2=t; t=v01;v01=v02;v02=t; t=v11;v11=v12;v12=t; t=v21;v21=v22;v22=t; }

    // v1 = col0 of V, v2 = col1; v3 = v1 x v2 (right-handed, unit)
    float v3x = v10*v21 - v20*v11;
    float v3y = v20*v01 - v00*v21;
    float v3z = v00*v11 - v10*v01;

    // u1 = normalize(F v1)
    float u1x = F[0]*v00 + F[1]*v10 + F[2]*v20;
    float u1y = F[3]*v00 + F[4]*v10 + F[5]*v20;
    float u1z = F[6]*v00 + F[7]*v10 + F[8]*v20;
    float inv1 = __builtin_amdgcn_rsqf(fmaxf(u1x*u1x + u1y*u1y + u1z*u1z, 1e-30f));
    u1x *= inv1; u1y *= inv1; u1z *= inv1;

    // u2 = normalize(F v2 - (u1 . F v2) u1)
    float wx = F[0]*v01 + F[1]*v11 + F[2]*v21;
    float wy = F[3]*v01 + F[4]*v11 + F[5]*v21;
    float wz = F[6]*v01 + F[7]*v11 + F[8]*v21;
    float dd = u1x*wx + u1y*wy + u1z*wz;
    wx -= dd*u1x; wy -= dd*u1y; wz -= dd*u1z;
    float inv2 = __builtin_amdgcn_rsqf(fmaxf(wx*wx + wy*wy + wz*wz, 1e-30f));
    float u2x = wx*inv2, u2y = wy*inv2, u2z = wz*inv2;

    // u3 = u1 x u2 (right-handed)
    float u3x = u1y*u2z - u1z*u2y;
    float u3y = u1z*u2x - u1x*u2z;
    float u3z = u1x*u2y - u1y*u2x;

    // R = u1 v1^T + u2 v2^T + u3 v3^T  ==  U diag(1,1,det(UV^T)) V^T
    float Rm[9];
    Rm[0] = u1x*v00 + u2x*v01 + u3x*v3x;
    Rm[1] = u1x*v10 + u2x*v11 + u3x*v3y;
    Rm[2] = u1x*v20 + u2x*v21 + u3x*v3z;
    Rm[3] = u1y*v00 + u2y*v01 + u3y*v3x;
    Rm[4] = u1y*v10 + u2y*v11 + u3y*v3y;
    Rm[5] = u1y*v20 + u2y*v21 + u3y*v3z;
    Rm[6] = u1z*v00 + u2z*v01 + u3z*v3x;
    Rm[7] = u1z*v10 + u2z*v11 + u3z*v3y;
    Rm[8] = u1z*v20 + u2z*v21 + u3z*v3z;

    // ---- stage result through LDS for vectorized store
    __syncthreads();
    #pragma unroll
    for (int k = 0; k < 9; ++k) lds[tid * 9 + k] = Rm[k];
    __syncthreads();

    #pragma unroll
    for (int it = 0; it < 3; ++it) {
        int j = tid + it * TPB;
        if (j < F4PB) O4[j] = lds4[j];
    }
}

extern "C" void kernel_launch(void* const* d_in, const int* in_sizes, int n_in,
                              void* d_out, int out_size, void* d_ws, size_t ws_size,
                              hipStream_t stream) {
    const float* Rc = (const float*)d_in[0];   // R_clean (N,L,3,3)
    const float* Tt = (const float*)d_in[1];   // t (N,)
    const float* Nz = (const float*)d_in[2];   // noise
    const float* Ez = (const float*)d_in[3];   // eps_noise
    float* Out = (float*)d_out;

    const long long mats = (long long)in_sizes[0] / 9;   // 2097152
    const int L = (int)(mats / in_sizes[1]);             // 8192
    const int blocks = (int)(mats / MPB);                // 8192

    so3_proj_kernel<<<blocks, TPB, 0, stream>>>(Rc, Tt, Nz, Ez, Out, L);
}